// Round 1
// baseline (330.786 us; speedup 1.0000x reference)
//
#include <hip/hip_runtime.h>
#include <hip/hip_bf16.h>

// Problem constants (B=4, S=2048 -> 8192 tokens; D=O=1024; E=8; top-2)
#define NTOK 8192
#define DDIM 1024
#define ODIM 1024
#define NEXP 8

typedef __attribute__((ext_vector_type(8))) short short8;
typedef __attribute__((ext_vector_type(4))) float f32x4;

// ---- workspace layout (bytes) ----
#define CNT_OFF   0u                       // 8 ints
#define SC_OFF    256u                     // 8192*2 floats = 64 KiB
#define LIST_OFF  (256u + NTOK*2u*4u)      // 8*8192 ints = 256 KiB
#define XH_OFF    (1u<<20)                 // bf16 x, 16 MiB
#define WH_OFF    ((1u<<20) + NTOK*DDIM*2u) // bf16 W, 16 MiB
// total ~33 MiB

__device__ inline unsigned short f2bf(float f) {
    unsigned int u = __float_as_uint(f);
    unsigned int r = (u + 0x7FFFu + ((u >> 16) & 1u)) >> 16;   // RNE
    return (unsigned short)r;
}

__device__ inline void glds16(const unsigned short* g, unsigned short* l) {
    __builtin_amdgcn_global_load_lds(
        (const __attribute__((address_space(1))) unsigned int*)g,
        (__attribute__((address_space(3))) unsigned int*)l, 16, 0, 0);
}

__global__ void k_zero(int* counts) {
    if (threadIdx.x < NEXP) counts[threadIdx.x] = 0;
}

// fp32 -> bf16 conversion, 4 elems/thread
__global__ void k_cvt(const float4* __restrict__ src, ushort4* __restrict__ dst, int n4) {
    int i = blockIdx.x * blockDim.x + threadIdx.x;
    if (i >= n4) return;
    float4 v = src[i];
    ushort4 o;
    o.x = f2bf(v.x); o.y = f2bf(v.y); o.z = f2bf(v.z); o.w = f2bf(v.w);
    dst[i] = o;
}

// One wave per token: fp64-accum gate logits, softmax, top-2, expert lists,
// and out init = s0*b[e0] + s1*b[e1].
__global__ __launch_bounds__(256) void k_gate(
    const float* __restrict__ x, const float* __restrict__ Wg,
    const float* __restrict__ bg, const float* __restrict__ b,
    float* __restrict__ out, float* __restrict__ scores2,
    int* __restrict__ lists, int* __restrict__ counts)
{
    const int wave = threadIdx.x >> 6, lane = threadIdx.x & 63;
    const int t = blockIdx.x * 4 + wave;
    if (t >= NTOK) return;

    const float* xr = x + (size_t)t * DDIM;
    float xv[16];
    #pragma unroll
    for (int i = 0; i < 16; i++) xv[i] = xr[lane + 64 * i];

    double lg[NEXP];
    #pragma unroll
    for (int e = 0; e < NEXP; e++) {
        const float* wr = Wg + (size_t)e * DDIM;
        double a = 0.0;
        #pragma unroll
        for (int i = 0; i < 16; i++) a += (double)xv[i] * (double)wr[lane + 64 * i];
        #pragma unroll
        for (int off = 32; off > 0; off >>= 1) a += __shfl_down(a, off);
        lg[e] = a;   // valid on lane 0
    }

    int i0 = 0, i1 = 0;
    float s0 = 0.f, s1 = 0.f;
    if (lane == 0) {
        double best = -1e300, sec = -1e300; int bi = -1, si = -1;
        #pragma unroll
        for (int e = 0; e < NEXP; e++) {
            double v = lg[e] + (double)bg[e];
            if (v > best) { sec = best; si = bi; best = v; bi = e; }
            else if (v > sec) { sec = v; si = e; }
        }
        double sum = 0.0;
        #pragma unroll
        for (int e = 0; e < NEXP; e++) sum += exp(lg[e] + (double)bg[e] - best);
        s0 = (float)(1.0 / sum);            // exp(best-best)=1
        s1 = (float)(exp(sec - best) / sum);
        i0 = bi; i1 = si;
        scores2[t * 2 + 0] = s0;
        scores2[t * 2 + 1] = s1;
        int p0 = atomicAdd(&counts[i0], 1);
        lists[i0 * NTOK + p0] = t * 2 + 0;
        int p1 = atomicAdd(&counts[i1], 1);
        lists[i1 * NTOK + p1] = t * 2 + 1;
    }
    i0 = __shfl(i0, 0); i1 = __shfl(i1, 0);
    s0 = __shfl(s0, 0); s1 = __shfl(s1, 0);

    const float* b0 = b + (size_t)i0 * ODIM;
    const float* b1 = b + (size_t)i1 * ODIM;
    float* orow = out + (size_t)t * ODIM;
    #pragma unroll
    for (int i = 0; i < 16; i++) {
        int o = lane + 64 * i;
        orow[o] = s0 * b0[o] + s1 * b1[o];
    }
}

// Grouped GEMM: per expert, rows = gathered tokens (top-2 membership),
// out[tok, :] += score * (x[tok, :] @ W[e]^T). 128x128 tile, BK=32,
// 4 waves (2x2), 16x16x32 bf16 MFMA, global_load_lds staging.
__global__ __launch_bounds__(256) void k_gemm(
    const unsigned short* __restrict__ xh, const unsigned short* __restrict__ wh,
    const int* __restrict__ counts, const int* __restrict__ lists,
    const float* __restrict__ scores2, float* __restrict__ out)
{
    __shared__ __align__(16) unsigned short As[128 * 32];
    __shared__ __align__(16) unsigned short Bs[128 * 32];

    int bid = (int)blockIdx.x;
    int e = -1, mt = 0, nt = 0, cnt = 0;
    #pragma unroll
    for (int ee = 0; ee < NEXP; ee++) {
        int c = counts[ee];
        int tiles = ((c + 127) >> 7) * 8;      // 8 = ODIM/128
        if (e < 0) {
            if (bid < tiles) { e = ee; mt = bid >> 3; nt = bid & 7; cnt = c; }
            else bid -= tiles;
        }
    }
    if (e < 0) return;

    const int m0 = mt * 128, n0 = nt * 128;
    const int* list = lists + e * NTOK;
    const int tid = threadIdx.x, wid = tid >> 6, lane = tid & 63;

    // staging: wave wid covers rows [wid*16, wid*16+16) and +64; lane -> (row=lane>>2, seg=lane&3)
    const int ar0 = wid * 16 + (lane >> 2);
    const int ar1 = 64 + ar0;
    int g0 = m0 + ar0; if (g0 >= cnt) g0 = cnt - 1;
    int g1 = m0 + ar1; if (g1 >= cnt) g1 = cnt - 1;
    const int tok0 = list[g0] >> 1;
    const int tok1 = list[g1] >> 1;
    const int seg = (lane & 3) * 8;
    const unsigned short* aS0 = xh + (size_t)tok0 * DDIM + seg;
    const unsigned short* aS1 = xh + (size_t)tok1 * DDIM + seg;
    const unsigned short* bBase = wh + (size_t)e * ODIM * DDIM;
    const unsigned short* bS0 = bBase + (size_t)(n0 + ar0) * DDIM + seg;
    const unsigned short* bS1 = bBase + (size_t)(n0 + ar1) * DDIM + seg;
    unsigned short* aL0 = &As[(wid * 16) * 32];
    unsigned short* aL1 = &As[(64 + wid * 16) * 32];
    unsigned short* bL0 = &Bs[(wid * 16) * 32];
    unsigned short* bL1 = &Bs[(64 + wid * 16) * 32];

    const int wm = wid >> 1, wn = wid & 1;
    const int fr = lane & 15, fk = (lane >> 4) * 8;

    f32x4 acc[4][4];
    #pragma unroll
    for (int m = 0; m < 4; m++)
        #pragma unroll
        for (int n = 0; n < 4; n++)
            acc[m][n] = (f32x4){0.f, 0.f, 0.f, 0.f};

    for (int k0 = 0; k0 < DDIM; k0 += 32) {
        glds16(aS0 + k0, aL0);
        glds16(aS1 + k0, aL1);
        glds16(bS0 + k0, bL0);
        glds16(bS1 + k0, bL1);
        __syncthreads();
        short8 af[4], bf_[4];
        #pragma unroll
        for (int m = 0; m < 4; m++)
            af[m] = *(const short8*)&As[(wm * 64 + m * 16 + fr) * 32 + fk];
        #pragma unroll
        for (int n = 0; n < 4; n++)
            bf_[n] = *(const short8*)&Bs[(wn * 64 + n * 16 + fr) * 32 + fk];
        #pragma unroll
        for (int m = 0; m < 4; m++)
            #pragma unroll
            for (int n = 0; n < 4; n++)
                acc[m][n] = __builtin_amdgcn_mfma_f32_16x16x32_bf16(af[m], bf_[n], acc[m][n], 0, 0, 0);
        __syncthreads();
    }

    // scatter-accumulate: out[tok, n0+col] += s * acc  (C/D: col=lane&15, row=(lane>>4)*4+j)
    #pragma unroll
    for (int m = 0; m < 4; m++) {
        #pragma unroll
        for (int j = 0; j < 4; j++) {
            int r = wm * 64 + m * 16 + (lane >> 4) * 4 + j;
            int gr = m0 + r;
            if (gr < cnt) {
                int entry = list[gr];
                int tok = entry >> 1;
                float s = scores2[entry];
                float* orow = out + (size_t)tok * ODIM + n0 + wn * 64 + (lane & 15);
                #pragma unroll
                for (int n = 0; n < 4; n++)
                    atomicAdd(orow + n * 16, s * acc[m][n][j]);
            }
        }
    }
}

extern "C" void kernel_launch(void* const* d_in, const int* in_sizes, int n_in,
                              void* d_out, int out_size, void* d_ws, size_t ws_size,
                              hipStream_t stream) {
    const float* x  = (const float*)d_in[0];
    const float* W  = (const float*)d_in[1];
    const float* b  = (const float*)d_in[2];
    const float* Wg = (const float*)d_in[3];
    const float* bg = (const float*)d_in[4];
    float* out = (float*)d_out;
    char* ws = (char*)d_ws;

    int*   counts  = (int*)(ws + CNT_OFF);
    float* scores2 = (float*)(ws + SC_OFF);
    int*   lists   = (int*)(ws + LIST_OFF);
    unsigned short* xh = (unsigned short*)(ws + XH_OFF);
    unsigned short* wh = (unsigned short*)(ws + WH_OFF);

    k_zero<<<1, 64, 0, stream>>>(counts);

    int n4x = NTOK * DDIM / 4;
    k_cvt<<<n4x / 256, 256, 0, stream>>>((const float4*)x, (ushort4*)xh, n4x);
    int n4w = NEXP * ODIM * DDIM / 4;
    k_cvt<<<n4w / 256, 256, 0, stream>>>((const float4*)W, (ushort4*)wh, n4w);

    k_gate<<<NTOK / 4, 256, 0, stream>>>(x, Wg, bg, b, out, scores2, lists, counts);

    // worst-case tiles: sum_e ceil(cnt_e/128)*8 <= (128+8)*8 = 1088
    k_gemm<<<1088, 256, 0, stream>>>(xh, wh, counts, lists, scores2, out);
}

// Round 2
// 176.964 us; speedup vs baseline: 1.8692x; 1.8692x over previous
//
#include <hip/hip_runtime.h>
#include <hip/hip_bf16.h>

// Problem constants (B=4, S=2048 -> 8192 tokens; D=O=1024; E=8; top-2)
#define NTOK 8192
#define DDIM 1024
#define ODIM 1024
#define NEXP 8

typedef __attribute__((ext_vector_type(8))) short short8;
typedef __attribute__((ext_vector_type(4))) float f32x4;

// ---- workspace layout (bytes) ----
#define CNT_OFF   0u                       // 8 ints
#define SC_OFF    256u                     // 8192*2 floats = 64 KiB
#define LIST_OFF  (256u + NTOK*2u*4u)      // 8*8192 ints = 256 KiB
#define XH_OFF    (1u<<20)                 // bf16 x, 16 MiB
#define WH_OFF    ((1u<<20) + NTOK*DDIM*2u) // bf16 W, 16 MiB

__device__ inline unsigned short f2bf(float f) {
    unsigned int u = __float_as_uint(f);
    unsigned int r = (u + 0x7FFFu + ((u >> 16) & 1u)) >> 16;   // RNE
    return (unsigned short)r;
}

__device__ inline void glds16(const unsigned short* g, unsigned short* l) {
    __builtin_amdgcn_global_load_lds(
        (const __attribute__((address_space(1))) unsigned int*)g,
        (__attribute__((address_space(3))) unsigned int*)l, 16, 0, 0);
}

__global__ void k_zero(int* counts) {
    if (threadIdx.x < NEXP) counts[threadIdx.x] = 0;
}

// fp32 -> bf16 conversion, 4 elems/thread
__global__ void k_cvt(const float4* __restrict__ src, ushort4* __restrict__ dst, int n4) {
    int i = blockIdx.x * blockDim.x + threadIdx.x;
    if (i >= n4) return;
    float4 v = src[i];
    ushort4 o;
    o.x = f2bf(v.x); o.y = f2bf(v.y); o.z = f2bf(v.z); o.w = f2bf(v.w);
    dst[i] = o;
}

// Gating: 256 blocks x 32 tokens. Wave-per-token (8 tokens/wave, sequential),
// fp64-accum logits via float4 loads + xor-butterfly reduce (all lanes get
// result). Expert ids recorded in LDS; ONE global atomic per (block,expert)
// instead of per token (round 1: 16384 contended atomics = 209us).
// out init = s0*b[e0] + s1*b[e1] fused, float4-vectorized.
__global__ __launch_bounds__(256) void k_gate(
    const float* __restrict__ x, const float* __restrict__ Wg,
    const float* __restrict__ bg, const float* __restrict__ b,
    float* __restrict__ out, float* __restrict__ scores2,
    int* __restrict__ lists, int* __restrict__ counts)
{
    __shared__ unsigned char s_eid[64];     // 32 tokens * 2 entries
    const int tid = threadIdx.x, wave = tid >> 6, lane = tid & 63;
    const int tblk = blockIdx.x * 32;

    double bgv[NEXP];
    #pragma unroll
    for (int e = 0; e < NEXP; e++) bgv[e] = (double)bg[e];

    for (int ti = 0; ti < 8; ti++) {
        const int t = tblk + wave * 8 + ti;
        const float* xr = x + (size_t)t * DDIM;
        float4 xv[4];
        #pragma unroll
        for (int i = 0; i < 4; i++)
            xv[i] = *(const float4*)&xr[lane * 4 + 256 * i];

        double lg[NEXP];
        #pragma unroll
        for (int e = 0; e < NEXP; e++) {
            const float* wr = Wg + (size_t)e * DDIM;
            double a = 0.0;
            #pragma unroll
            for (int i = 0; i < 4; i++) {
                float4 wv = *(const float4*)&wr[lane * 4 + 256 * i];
                a += (double)xv[i].x * (double)wv.x + (double)xv[i].y * (double)wv.y
                   + (double)xv[i].z * (double)wv.z + (double)xv[i].w * (double)wv.w;
            }
            #pragma unroll
            for (int off = 32; off > 0; off >>= 1) a += __shfl_xor(a, off);
            lg[e] = a + bgv[e];             // all lanes hold full logit
        }

        // top-2 (stable: earliest index wins ties, matches lax.top_k)
        int i0 = -1, i1 = -1;
        double best = -1e300, sec = -1e300;
        #pragma unroll
        for (int e = 0; e < NEXP; e++) {
            double v = lg[e];
            if (v > best) { sec = best; i1 = i0; best = v; i0 = e; }
            else if (v > sec) { sec = v; i1 = e; }
        }
        double sum = 0.0;
        #pragma unroll
        for (int e = 0; e < NEXP; e++) sum += exp(lg[e] - best);
        float s0 = (float)(1.0 / sum);
        float s1 = (float)(exp(sec - best) / sum);

        if (lane == 0) {
            scores2[t * 2 + 0] = s0;
            scores2[t * 2 + 1] = s1;
            int le = (wave * 8 + ti) * 2;
            s_eid[le + 0] = (unsigned char)i0;
            s_eid[le + 1] = (unsigned char)i1;
        }

        const float* b0 = b + (size_t)i0 * ODIM;
        const float* b1 = b + (size_t)i1 * ODIM;
        float* orow = out + (size_t)t * ODIM;
        #pragma unroll
        for (int i = 0; i < 4; i++) {
            int o = lane * 4 + 256 * i;
            float4 v0 = *(const float4*)&b0[o];
            float4 v1 = *(const float4*)&b1[o];
            float4 r;
            r.x = s0 * v0.x + s1 * v1.x;
            r.y = s0 * v0.y + s1 * v1.y;
            r.z = s0 * v0.z + s1 * v1.z;
            r.w = s0 * v0.w + s1 * v1.w;
            *(float4*)&orow[o] = r;
        }
    }
    __syncthreads();

    // per-expert scatter: thread e owns expert e; one global atomic each
    if (tid < NEXP) {
        int c = 0;
        for (int j = 0; j < 64; j++) c += (s_eid[j] == tid);
        if (c) {
            int p = atomicAdd(&counts[tid], c);
            for (int j = 0; j < 64; j++)
                if (s_eid[j] == tid)
                    lists[tid * NTOK + (p++)] = (tblk + (j >> 1)) * 2 + (j & 1);
        }
    }
}

// Grouped GEMM: per expert, rows = gathered tokens (top-2 membership),
// out[tok, :] += score * (x[tok, :] @ W[e]^T). 128x128 tile, BK=32,
// 4 waves (2x2), 16x16x32 bf16 MFMA, global_load_lds staging.
__global__ __launch_bounds__(256) void k_gemm(
    const unsigned short* __restrict__ xh, const unsigned short* __restrict__ wh,
    const int* __restrict__ counts, const int* __restrict__ lists,
    const float* __restrict__ scores2, float* __restrict__ out)
{
    __shared__ __align__(16) unsigned short As[128 * 32];
    __shared__ __align__(16) unsigned short Bs[128 * 32];

    int bid = (int)blockIdx.x;
    int e = -1, mt = 0, nt = 0, cnt = 0;
    #pragma unroll
    for (int ee = 0; ee < NEXP; ee++) {
        int c = counts[ee];
        int tiles = ((c + 127) >> 7) * 8;      // 8 = ODIM/128
        if (e < 0) {
            if (bid < tiles) { e = ee; mt = bid >> 3; nt = bid & 7; cnt = c; }
            else bid -= tiles;
        }
    }
    if (e < 0) return;

    const int m0 = mt * 128, n0 = nt * 128;
    const int* list = lists + e * NTOK;
    const int tid = threadIdx.x, wid = tid >> 6, lane = tid & 63;

    const int ar0 = wid * 16 + (lane >> 2);
    const int ar1 = 64 + ar0;
    int g0 = m0 + ar0; if (g0 >= cnt) g0 = cnt - 1;
    int g1 = m0 + ar1; if (g1 >= cnt) g1 = cnt - 1;
    const int tok0 = list[g0] >> 1;
    const int tok1 = list[g1] >> 1;
    const int seg = (lane & 3) * 8;
    const unsigned short* aS0 = xh + (size_t)tok0 * DDIM + seg;
    const unsigned short* aS1 = xh + (size_t)tok1 * DDIM + seg;
    const unsigned short* bBase = wh + (size_t)e * ODIM * DDIM;
    const unsigned short* bS0 = bBase + (size_t)(n0 + ar0) * DDIM + seg;
    const unsigned short* bS1 = bBase + (size_t)(n0 + ar1) * DDIM + seg;
    unsigned short* aL0 = &As[(wid * 16) * 32];
    unsigned short* aL1 = &As[(64 + wid * 16) * 32];
    unsigned short* bL0 = &Bs[(wid * 16) * 32];
    unsigned short* bL1 = &Bs[(64 + wid * 16) * 32];

    const int wm = wid >> 1, wn = wid & 1;
    const int fr = lane & 15, fk = (lane >> 4) * 8;

    f32x4 acc[4][4];
    #pragma unroll
    for (int m = 0; m < 4; m++)
        #pragma unroll
        for (int n = 0; n < 4; n++)
            acc[m][n] = (f32x4){0.f, 0.f, 0.f, 0.f};

    for (int k0 = 0; k0 < DDIM; k0 += 32) {
        glds16(aS0 + k0, aL0);
        glds16(aS1 + k0, aL1);
        glds16(bS0 + k0, bL0);
        glds16(bS1 + k0, bL1);
        __syncthreads();
        short8 af[4], bf_[4];
        #pragma unroll
        for (int m = 0; m < 4; m++)
            af[m] = *(const short8*)&As[(wm * 64 + m * 16 + fr) * 32 + fk];
        #pragma unroll
        for (int n = 0; n < 4; n++)
            bf_[n] = *(const short8*)&Bs[(wn * 64 + n * 16 + fr) * 32 + fk];
        #pragma unroll
        for (int m = 0; m < 4; m++)
            #pragma unroll
            for (int n = 0; n < 4; n++)
                acc[m][n] = __builtin_amdgcn_mfma_f32_16x16x32_bf16(af[m], bf_[n], acc[m][n], 0, 0, 0);
        __syncthreads();
    }

    #pragma unroll
    for (int m = 0; m < 4; m++) {
        #pragma unroll
        for (int j = 0; j < 4; j++) {
            int r = wm * 64 + m * 16 + (lane >> 4) * 4 + j;
            int gr = m0 + r;
            if (gr < cnt) {
                int entry = list[gr];
                int tok = entry >> 1;
                float s = scores2[entry];
                float* orow = out + (size_t)tok * ODIM + n0 + wn * 64 + (lane & 15);
                #pragma unroll
                for (int n = 0; n < 4; n++)
                    atomicAdd(orow + n * 16, s * acc[m][n][j]);
            }
        }
    }
}

extern "C" void kernel_launch(void* const* d_in, const int* in_sizes, int n_in,
                              void* d_out, int out_size, void* d_ws, size_t ws_size,
                              hipStream_t stream) {
    const float* x  = (const float*)d_in[0];
    const float* W  = (const float*)d_in[1];
    const float* b  = (const float*)d_in[2];
    const float* Wg = (const float*)d_in[3];
    const float* bg = (const float*)d_in[4];
    float* out = (float*)d_out;
    char* ws = (char*)d_ws;

    int*   counts  = (int*)(ws + CNT_OFF);
    float* scores2 = (float*)(ws + SC_OFF);
    int*   lists   = (int*)(ws + LIST_OFF);
    unsigned short* xh = (unsigned short*)(ws + XH_OFF);
    unsigned short* wh = (unsigned short*)(ws + WH_OFF);

    k_zero<<<1, 64, 0, stream>>>(counts);

    int n4x = NTOK * DDIM / 4;
    k_cvt<<<n4x / 256, 256, 0, stream>>>((const float4*)x, (ushort4*)xh, n4x);
    int n4w = NEXP * ODIM * DDIM / 4;
    k_cvt<<<n4w / 256, 256, 0, stream>>>((const float4*)W, (ushort4*)wh, n4w);

    k_gate<<<NTOK / 32, 256, 0, stream>>>(x, Wg, bg, b, out, scores2, lists, counts);

    // worst-case tiles: sum_e ceil(cnt_e/128)*8 <= (128+7)*8 = 1080
    k_gemm<<<1088, 256, 0, stream>>>(xh, wh, counts, lists, scores2, out);
}

// Round 3
// 168.289 us; speedup vs baseline: 1.9656x; 1.0515x over previous
//
#include <hip/hip_runtime.h>
#include <hip/hip_bf16.h>

// Problem constants (B=4, S=2048 -> 8192 tokens; D=O=1024; E=8; top-2)
#define NTOK 8192
#define DDIM 1024
#define ODIM 1024
#define NEXP 8
#define BK   64
#define NKT  (DDIM / BK)     // 16 K-tiles

typedef __attribute__((ext_vector_type(8))) short short8;
typedef __attribute__((ext_vector_type(4))) float f32x4;

// ---- workspace layout (bytes) ----
#define CNT_OFF   0u
#define SC_OFF    256u
#define LIST_OFF  (256u + NTOK*2u*4u)
#define XH_OFF    (1u<<20)
#define WH_OFF    ((1u<<20) + NTOK*DDIM*2u)

__device__ inline unsigned short f2bf(float f) {
    unsigned int u = __float_as_uint(f);
    unsigned int r = (u + 0x7FFFu + ((u >> 16) & 1u)) >> 16;   // RNE
    return (unsigned short)r;
}

__device__ inline void glds16(const unsigned short* g, unsigned short* l) {
    __builtin_amdgcn_global_load_lds(
        (const __attribute__((address_space(1))) unsigned int*)g,
        (__attribute__((address_space(3))) unsigned int*)l, 16, 0, 0);
}

__global__ void k_zero(int* counts) {
    if (threadIdx.x < NEXP) counts[threadIdx.x] = 0;
}

// fp32 -> bf16 conversion (W only; x conversion fused into k_gate)
__global__ void k_cvt(const float4* __restrict__ src, ushort4* __restrict__ dst, int n4) {
    int i = blockIdx.x * blockDim.x + threadIdx.x;
    if (i >= n4) return;
    float4 v = src[i];
    ushort4 o;
    o.x = f2bf(v.x); o.y = f2bf(v.y); o.z = f2bf(v.z); o.w = f2bf(v.w);
    dst[i] = o;
}

// Gating: 256 blocks x 32 tokens, wave-per-token (8 sequential each).
// fp64 logits via float4 loads + xor-butterfly; block-aggregated list scatter
// (one atomic per block,expert). Fused: bf16 conversion of x, and
// out init = s0*b[e0] + s1*b[e1].
__global__ __launch_bounds__(256) void k_gate(
    const float* __restrict__ x, const float* __restrict__ Wg,
    const float* __restrict__ bg, const float* __restrict__ b,
    float* __restrict__ out, float* __restrict__ scores2,
    int* __restrict__ lists, int* __restrict__ counts,
    unsigned short* __restrict__ xh)
{
    __shared__ unsigned char s_eid[64];     // 32 tokens * 2 entries
    const int tid = threadIdx.x, wave = tid >> 6, lane = tid & 63;
    const int tblk = blockIdx.x * 32;

    double bgv[NEXP];
    #pragma unroll
    for (int e = 0; e < NEXP; e++) bgv[e] = (double)bg[e];

    for (int ti = 0; ti < 8; ti++) {
        const int t = tblk + wave * 8 + ti;
        const float* xr = x + (size_t)t * DDIM;
        float4 xv[4];
        #pragma unroll
        for (int i = 0; i < 4; i++)
            xv[i] = *(const float4*)&xr[lane * 4 + 256 * i];

        // fused bf16 conversion of x (row written once, coalesced 8B/lane)
        unsigned short* xhr = xh + (size_t)t * DDIM;
        #pragma unroll
        for (int i = 0; i < 4; i++) {
            ushort4 h;
            h.x = f2bf(xv[i].x); h.y = f2bf(xv[i].y);
            h.z = f2bf(xv[i].z); h.w = f2bf(xv[i].w);
            *(ushort4*)&xhr[lane * 4 + 256 * i] = h;
        }

        double lg[NEXP];
        #pragma unroll
        for (int e = 0; e < NEXP; e++) {
            const float* wr = Wg + (size_t)e * DDIM;
            double a = 0.0;
            #pragma unroll
            for (int i = 0; i < 4; i++) {
                float4 wv = *(const float4*)&wr[lane * 4 + 256 * i];
                a += (double)xv[i].x * (double)wv.x + (double)xv[i].y * (double)wv.y
                   + (double)xv[i].z * (double)wv.z + (double)xv[i].w * (double)wv.w;
            }
            #pragma unroll
            for (int off = 32; off > 0; off >>= 1) a += __shfl_xor(a, off);
            lg[e] = a + bgv[e];
        }

        int i0 = -1, i1 = -1;
        double best = -1e300, sec = -1e300;
        #pragma unroll
        for (int e = 0; e < NEXP; e++) {
            double v = lg[e];
            if (v > best) { sec = best; i1 = i0; best = v; i0 = e; }
            else if (v > sec) { sec = v; i1 = e; }
        }
        double sum = 0.0;
        #pragma unroll
        for (int e = 0; e < NEXP; e++) sum += exp(lg[e] - best);
        float s0 = (float)(1.0 / sum);
        float s1 = (float)(exp(sec - best) / sum);

        if (lane == 0) {
            scores2[t * 2 + 0] = s0;
            scores2[t * 2 + 1] = s1;
            int le = (wave * 8 + ti) * 2;
            s_eid[le + 0] = (unsigned char)i0;
            s_eid[le + 1] = (unsigned char)i1;
        }

        const float* b0 = b + (size_t)i0 * ODIM;
        const float* b1 = b + (size_t)i1 * ODIM;
        float* orow = out + (size_t)t * ODIM;
        #pragma unroll
        for (int i = 0; i < 4; i++) {
            int o = lane * 4 + 256 * i;
            float4 v0 = *(const float4*)&b0[o];
            float4 v1 = *(const float4*)&b1[o];
            float4 r;
            r.x = s0 * v0.x + s1 * v1.x;
            r.y = s0 * v0.y + s1 * v1.y;
            r.z = s0 * v0.z + s1 * v1.z;
            r.w = s0 * v0.w + s1 * v1.w;
            *(float4*)&orow[o] = r;
        }
    }
    __syncthreads();

    if (tid < NEXP) {
        int c = 0;
        for (int j = 0; j < 64; j++) c += (s_eid[j] == tid);
        if (c) {
            int p = atomicAdd(&counts[tid], c);
            for (int j = 0; j < 64; j++)
                if (s_eid[j] == tid)
                    lists[tid * NTOK + (p++)] = (tblk + (j >> 1)) * 2 + (j & 1);
        }
    }
}

// Grouped GEMM, 128x128 tile, BK=64, double-buffered LDS with XOR swizzle.
// LDS layout: [row][seg_phys] where seg_phys = seg_log ^ (row&7), segs of 16B,
// rows of 128B. global_load_lds writes linearly; the per-lane GLOBAL source is
// inverse-swizzled; ds_read applies the same swizzle. 2-phase schedule: one
// barrier per K-tile; stage(t+1) issued after it, hidden under tile-t compute.
__global__ __launch_bounds__(256, 2) void k_gemm(
    const unsigned short* __restrict__ xh, const unsigned short* __restrict__ wh,
    const int* __restrict__ counts, const int* __restrict__ lists,
    const float* __restrict__ scores2, float* __restrict__ out)
{
    __shared__ __align__(16) unsigned short As[2][128 * BK];
    __shared__ __align__(16) unsigned short Bs[2][128 * BK];

    // bijective chunked XCD swizzle (gridDim 1088 % 8 == 0): one m-panel's
    // 8 n-tiles stay on one XCD -> A-panel fetched once per XCD chunk.
    const int nwg = (int)gridDim.x;
    int bid = ((int)blockIdx.x & 7) * (nwg >> 3) + ((int)blockIdx.x >> 3);

    int e = -1, mt = 0, nt = 0, cnt = 0;
    #pragma unroll
    for (int ee = 0; ee < NEXP; ee++) {
        int c = counts[ee];
        int tiles = ((c + 127) >> 7) * 8;
        if (e < 0) {
            if (bid < tiles) { e = ee; mt = bid >> 3; nt = bid & 7; cnt = c; }
            else bid -= tiles;
        }
    }
    if (e < 0) return;

    const int m0 = mt * 128, n0 = nt * 128;
    const int* list = lists + e * NTOK;
    const int tid = threadIdx.x, wid = tid >> 6, lane = tid & 63;

    // ---- staging setup: 4 glds16 per matrix per thread, 8 rows each ----
    const int l8 = lane >> 3, s8 = lane & 7;
    const int co = ((s8 ^ l8) << 3);            // inverse-swizzled column (elems)
    const unsigned short* whE = wh + (size_t)e * ODIM * DDIM;
    const unsigned short* aSrc[4];
    const unsigned short* bSrc[4];
    int rbase[4];
    #pragma unroll
    for (int i = 0; i < 4; i++) {
        int rb = (wid * 4 + i) * 8;
        rbase[i] = rb;
        int r = rb + l8;
        int g = m0 + r; if (g >= cnt) g = cnt - 1;
        aSrc[i] = xh + (size_t)(list[g] >> 1) * DDIM + co;
        bSrc[i] = whE + (size_t)(n0 + r) * DDIM + co;
    }

    const int wm = wid >> 1, wn = wid & 1;
    const int fr = lane & 15, g4 = lane >> 4;
    const int fx0 = ((g4 ^ (fr & 7)) << 3);          // kk=0 swizzled elem offset
    const int fx1 = (((4 + g4) ^ (fr & 7)) << 3);    // kk=1

    f32x4 acc[4][4];
    #pragma unroll
    for (int m = 0; m < 4; m++)
        #pragma unroll
        for (int n = 0; n < 4; n++)
            acc[m][n] = (f32x4){0.f, 0.f, 0.f, 0.f};

    // prologue: stage tile 0 into buf 0
    #pragma unroll
    for (int i = 0; i < 4; i++) {
        glds16(aSrc[i], &As[0][rbase[i] * BK]);
        glds16(bSrc[i], &Bs[0][rbase[i] * BK]);
    }

    int buf = 0;
    for (int t = 0; t < NKT; t++) {
        __syncthreads();                        // drains vmcnt: stage(t) landed
        if (t + 1 < NKT) {
            const int k0 = (t + 1) * BK;
            #pragma unroll
            for (int i = 0; i < 4; i++) {
                glds16(aSrc[i] + k0, &As[buf ^ 1][rbase[i] * BK]);
                glds16(bSrc[i] + k0, &Bs[buf ^ 1][rbase[i] * BK]);
            }
        }
        short8 af[4][2], bfr[4][2];
        #pragma unroll
        for (int m = 0; m < 4; m++) {
            const int row = (wm * 64 + m * 16 + fr) * BK;
            af[m][0] = *(const short8*)&As[buf][row + fx0];
            af[m][1] = *(const short8*)&As[buf][row + fx1];
        }
        #pragma unroll
        for (int n = 0; n < 4; n++) {
            const int row = (wn * 64 + n * 16 + fr) * BK;
            bfr[n][0] = *(const short8*)&Bs[buf][row + fx0];
            bfr[n][1] = *(const short8*)&Bs[buf][row + fx1];
        }
        #pragma unroll
        for (int kk = 0; kk < 2; kk++)
            #pragma unroll
            for (int m = 0; m < 4; m++)
                #pragma unroll
                for (int n = 0; n < 4; n++)
                    acc[m][n] = __builtin_amdgcn_mfma_f32_16x16x32_bf16(
                        af[m][kk], bfr[n][kk], acc[m][n], 0, 0, 0);
        buf ^= 1;
    }

    // scatter-accumulate epilogue (C/D: col=lane&15, row=(lane>>4)*4+j)
    #pragma unroll
    for (int m = 0; m < 4; m++) {
        #pragma unroll
        for (int j = 0; j < 4; j++) {
            int r = wm * 64 + m * 16 + g4 * 4 + j;
            int gr = m0 + r;
            if (gr < cnt) {
                int entry = list[gr];
                int tok = entry >> 1;
                float s = scores2[entry];
                float* orow = out + (size_t)tok * ODIM + n0 + wn * 64 + fr;
                #pragma unroll
                for (int n = 0; n < 4; n++)
                    atomicAdd(orow + n * 16, s * acc[m][n][j]);
            }
        }
    }
}

extern "C" void kernel_launch(void* const* d_in, const int* in_sizes, int n_in,
                              void* d_out, int out_size, void* d_ws, size_t ws_size,
                              hipStream_t stream) {
    const float* x  = (const float*)d_in[0];
    const float* W  = (const float*)d_in[1];
    const float* b  = (const float*)d_in[2];
    const float* Wg = (const float*)d_in[3];
    const float* bg = (const float*)d_in[4];
    float* out = (float*)d_out;
    char* ws = (char*)d_ws;

    int*   counts  = (int*)(ws + CNT_OFF);
    float* scores2 = (float*)(ws + SC_OFF);
    int*   lists   = (int*)(ws + LIST_OFF);
    unsigned short* xh = (unsigned short*)(ws + XH_OFF);
    unsigned short* wh = (unsigned short*)(ws + WH_OFF);

    k_zero<<<1, 64, 0, stream>>>(counts);

    int n4w = NEXP * ODIM * DDIM / 4;
    k_cvt<<<n4w / 256, 256, 0, stream>>>((const float4*)W, (ushort4*)wh, n4w);

    k_gate<<<NTOK / 32, 256, 0, stream>>>(x, Wg, bg, b, out, scores2, lists, counts, xh);

    // worst-case tiles: sum_e ceil(cnt_e/128)*8 <= (128+7)*8 = 1080 <= 1088
    k_gemm<<<1088, 256, 0, stream>>>(xh, wh, counts, lists, scores2, out);
}

// Round 4
// 167.508 us; speedup vs baseline: 1.9748x; 1.0047x over previous
//
#include <hip/hip_runtime.h>
#include <hip/hip_bf16.h>

// Problem constants (B=4, S=2048 -> 8192 tokens; D=O=1024; E=8; top-2)
#define NTOK 8192
#define DDIM 1024
#define ODIM 1024
#define NEXP 8
#define BK   64
#define NKT  (DDIM / BK)     // 16 K-tiles

typedef __attribute__((ext_vector_type(8))) short short8;
typedef __attribute__((ext_vector_type(4))) float f32x4;

// ---- workspace layout (bytes) ----
#define CNT_OFF   0u                         // 16 ints (expert x rank)
#define SC_OFF    256u                       // 8192*2 floats = 64 KiB
#define LIST_OFF  (128u * 1024u)             // 16 * 8192 ints = 512 KiB
#define XH_OFF    (1u<<20)                   // bf16 x, 16 MiB
#define WH_OFF    ((1u<<20) + NTOK*DDIM*2u)  // bf16 W, 16 MiB

__device__ inline unsigned short f2bf(float f) {
    unsigned int u = __float_as_uint(f);
    unsigned int r = (u + 0x7FFFu + ((u >> 16) & 1u)) >> 16;   // RNE
    return (unsigned short)r;
}

__device__ inline void glds16(const unsigned short* g, unsigned short* l) {
    __builtin_amdgcn_global_load_lds(
        (const __attribute__((address_space(1))) unsigned int*)g,
        (__attribute__((address_space(3))) unsigned int*)l, 16, 0, 0);
}

__global__ void k_zero(int* counts) {
    if (threadIdx.x < 16) counts[threadIdx.x] = 0;
}

// fp32 -> bf16 conversion (W only; x conversion fused into k_gate)
__global__ void k_cvt(const float4* __restrict__ src, ushort4* __restrict__ dst, int n4) {
    int i = blockIdx.x * blockDim.x + threadIdx.x;
    if (i >= n4) return;
    float4 v = src[i];
    ushort4 o;
    o.x = f2bf(v.x); o.y = f2bf(v.y); o.z = f2bf(v.z); o.w = f2bf(v.w);
    dst[i] = o;
}

// Gating: 256 blocks x 32 tokens, wave-per-token (8 sequential each).
// fp64 logits via float4 loads + xor-butterfly; block-aggregated scatter into
// 16 lists (expert x rank) so each GEMM pass owns each output row exactly once.
// Fused: bf16 conversion of x, and out init = s0*b[e0] + s1*b[e1].
__global__ __launch_bounds__(256) void k_gate(
    const float* __restrict__ x, const float* __restrict__ Wg,
    const float* __restrict__ bg, const float* __restrict__ b,
    float* __restrict__ out, float* __restrict__ scores2,
    int* __restrict__ lists, int* __restrict__ counts,
    unsigned short* __restrict__ xh)
{
    __shared__ unsigned char s_eid[64];     // 32 tokens * 2 entries (rank interleaved)
    const int tid = threadIdx.x, wave = tid >> 6, lane = tid & 63;
    const int tblk = blockIdx.x * 32;

    double bgv[NEXP];
    #pragma unroll
    for (int e = 0; e < NEXP; e++) bgv[e] = (double)bg[e];

    for (int ti = 0; ti < 8; ti++) {
        const int t = tblk + wave * 8 + ti;
        const float* xr = x + (size_t)t * DDIM;
        float4 xv[4];
        #pragma unroll
        for (int i = 0; i < 4; i++)
            xv[i] = *(const float4*)&xr[lane * 4 + 256 * i];

        unsigned short* xhr = xh + (size_t)t * DDIM;
        #pragma unroll
        for (int i = 0; i < 4; i++) {
            ushort4 h;
            h.x = f2bf(xv[i].x); h.y = f2bf(xv[i].y);
            h.z = f2bf(xv[i].z); h.w = f2bf(xv[i].w);
            *(ushort4*)&xhr[lane * 4 + 256 * i] = h;
        }

        double lg[NEXP];
        #pragma unroll
        for (int e = 0; e < NEXP; e++) {
            const float* wr = Wg + (size_t)e * DDIM;
            double a = 0.0;
            #pragma unroll
            for (int i = 0; i < 4; i++) {
                float4 wv = *(const float4*)&wr[lane * 4 + 256 * i];
                a += (double)xv[i].x * (double)wv.x + (double)xv[i].y * (double)wv.y
                   + (double)xv[i].z * (double)wv.z + (double)xv[i].w * (double)wv.w;
            }
            #pragma unroll
            for (int off = 32; off > 0; off >>= 1) a += __shfl_xor(a, off);
            lg[e] = a + bgv[e];
        }

        int i0 = -1, i1 = -1;
        double best = -1e300, sec = -1e300;
        #pragma unroll
        for (int e = 0; e < NEXP; e++) {
            double v = lg[e];
            if (v > best) { sec = best; i1 = i0; best = v; i0 = e; }
            else if (v > sec) { sec = v; i1 = e; }
        }
        double sum = 0.0;
        #pragma unroll
        for (int e = 0; e < NEXP; e++) sum += exp(lg[e] - best);
        float s0 = (float)(1.0 / sum);
        float s1 = (float)(exp(sec - best) / sum);

        if (lane == 0) {
            scores2[t * 2 + 0] = s0;
            scores2[t * 2 + 1] = s1;
            int le = (wave * 8 + ti) * 2;
            s_eid[le + 0] = (unsigned char)i0;
            s_eid[le + 1] = (unsigned char)i1;
        }

        const float* b0 = b + (size_t)i0 * ODIM;
        const float* b1 = b + (size_t)i1 * ODIM;
        float* orow = out + (size_t)t * ODIM;
        #pragma unroll
        for (int i = 0; i < 4; i++) {
            int o = lane * 4 + 256 * i;
            float4 v0 = *(const float4*)&b0[o];
            float4 v1 = *(const float4*)&b1[o];
            float4 r;
            r.x = s0 * v0.x + s1 * v1.x;
            r.y = s0 * v0.y + s1 * v1.y;
            r.z = s0 * v0.z + s1 * v1.z;
            r.w = s0 * v0.w + s1 * v1.w;
            *(float4*)&orow[o] = r;
        }
    }
    __syncthreads();

    // 16 owners: e = tid&7, rank = tid>>3; one global atomic per (block,owner)
    if (tid < 16) {
        int e = tid & 7, kk = tid >> 3;
        int c = 0;
        for (int j = kk; j < 64; j += 2) c += (s_eid[j] == e);
        if (c) {
            int p = atomicAdd(&counts[tid], c);
            for (int j = kk; j < 64; j += 2)
                if (s_eid[j] == e)
                    lists[tid * NTOK + (p++)] = (tblk + (j >> 1)) * 2 + kk;
        }
    }
}

// Grouped GEMM, 128x128 tile, BK=64, double-buffered LDS with XOR swizzle.
// Called once per rank (two stream-ordered passes): within a pass every output
// row is owned by exactly one block -> plain RMW epilogue, no atomics.
__global__ __launch_bounds__(256, 2) void k_gemm(
    const unsigned short* __restrict__ xh, const unsigned short* __restrict__ wh,
    const int* __restrict__ counts, const int* __restrict__ lists,
    const float* __restrict__ scores2, float* __restrict__ out)
{
    __shared__ __align__(16) unsigned short As[2][128 * BK];
    __shared__ __align__(16) unsigned short Bs[2][128 * BK];

    // bijective chunked XCD swizzle (gridDim % 8 == 0)
    const int nwg = (int)gridDim.x;
    int bid = ((int)blockIdx.x & 7) * (nwg >> 3) + ((int)blockIdx.x >> 3);

    int e = -1, mt = 0, nt = 0, cnt = 0;
    #pragma unroll
    for (int ee = 0; ee < NEXP; ee++) {
        int c = counts[ee];
        int tiles = ((c + 127) >> 7) * 8;
        if (e < 0) {
            if (bid < tiles) { e = ee; mt = bid >> 3; nt = bid & 7; cnt = c; }
            else bid -= tiles;
        }
    }
    if (e < 0) return;

    const int m0 = mt * 128, n0 = nt * 128;
    const int* list = lists + e * NTOK;
    const int tid = threadIdx.x, wid = tid >> 6, lane = tid & 63;

    const int l8 = lane >> 3, s8 = lane & 7;
    const int co = ((s8 ^ l8) << 3);            // inverse-swizzled column (elems)
    const unsigned short* whE = wh + (size_t)e * ODIM * DDIM;
    const unsigned short* aSrc[4];
    const unsigned short* bSrc[4];
    int rbase[4];
    #pragma unroll
    for (int i = 0; i < 4; i++) {
        int rb = (wid * 4 + i) * 8;
        rbase[i] = rb;
        int r = rb + l8;
        int g = m0 + r; if (g >= cnt) g = cnt - 1;
        aSrc[i] = xh + (size_t)(list[g] >> 1) * DDIM + co;
        bSrc[i] = whE + (size_t)(n0 + r) * DDIM + co;
    }

    const int wm = wid >> 1, wn = wid & 1;
    const int fr = lane & 15, g4 = lane >> 4;
    const int fx0 = ((g4 ^ (fr & 7)) << 3);          // kk=0 swizzled elem offset
    const int fx1 = (((4 + g4) ^ (fr & 7)) << 3);    // kk=1

    f32x4 acc[4][4];
    #pragma unroll
    for (int m = 0; m < 4; m++)
        #pragma unroll
        for (int n = 0; n < 4; n++)
            acc[m][n] = (f32x4){0.f, 0.f, 0.f, 0.f};

    #pragma unroll
    for (int i = 0; i < 4; i++) {
        glds16(aSrc[i], &As[0][rbase[i] * BK]);
        glds16(bSrc[i], &Bs[0][rbase[i] * BK]);
    }

    int buf = 0;
    for (int t = 0; t < NKT; t++) {
        __syncthreads();
        if (t + 1 < NKT) {
            const int k0 = (t + 1) * BK;
            #pragma unroll
            for (int i = 0; i < 4; i++) {
                glds16(aSrc[i] + k0, &As[buf ^ 1][rbase[i] * BK]);
                glds16(bSrc[i] + k0, &Bs[buf ^ 1][rbase[i] * BK]);
            }
        }
        short8 af[4][2], bfr[4][2];
        #pragma unroll
        for (int m = 0; m < 4; m++) {
            const int row = (wm * 64 + m * 16 + fr) * BK;
            af[m][0] = *(const short8*)&As[buf][row + fx0];
            af[m][1] = *(const short8*)&As[buf][row + fx1];
        }
        #pragma unroll
        for (int n = 0; n < 4; n++) {
            const int row = (wn * 64 + n * 16 + fr) * BK;
            bfr[n][0] = *(const short8*)&Bs[buf][row + fx0];
            bfr[n][1] = *(const short8*)&Bs[buf][row + fx1];
        }
        #pragma unroll
        for (int kk = 0; kk < 2; kk++)
            #pragma unroll
            for (int m = 0; m < 4; m++)
                #pragma unroll
                for (int n = 0; n < 4; n++)
                    acc[m][n] = __builtin_amdgcn_mfma_f32_16x16x32_bf16(
                        af[m][kk], bfr[n][kk], acc[m][n], 0, 0, 0);
        buf ^= 1;
    }

    // race-free RMW epilogue (C/D: col=lane&15, row=(lane>>4)*4+j)
    #pragma unroll
    for (int m = 0; m < 4; m++) {
        #pragma unroll
        for (int j = 0; j < 4; j++) {
            int r = wm * 64 + m * 16 + g4 * 4 + j;
            int gr = m0 + r;
            if (gr < cnt) {
                int entry = list[gr];
                int tok = entry >> 1;
                float s = scores2[entry];
                float* orow = out + (size_t)tok * ODIM + n0 + wn * 64 + fr;
                #pragma unroll
                for (int n = 0; n < 4; n++)
                    orow[n * 16] += s * acc[m][n][j];
            }
        }
    }
}

extern "C" void kernel_launch(void* const* d_in, const int* in_sizes, int n_in,
                              void* d_out, int out_size, void* d_ws, size_t ws_size,
                              hipStream_t stream) {
    const float* x  = (const float*)d_in[0];
    const float* W  = (const float*)d_in[1];
    const float* b  = (const float*)d_in[2];
    const float* Wg = (const float*)d_in[3];
    const float* bg = (const float*)d_in[4];
    float* out = (float*)d_out;
    char* ws = (char*)d_ws;

    int*   counts  = (int*)(ws + CNT_OFF);    // [16]: rank0 experts, rank1 experts
    float* scores2 = (float*)(ws + SC_OFF);
    int*   lists   = (int*)(ws + LIST_OFF);   // [16][NTOK]
    unsigned short* xh = (unsigned short*)(ws + XH_OFF);
    unsigned short* wh = (unsigned short*)(ws + WH_OFF);

    k_zero<<<1, 64, 0, stream>>>(counts);

    int n4w = NEXP * ODIM * DDIM / 4;
    k_cvt<<<n4w / 256, 256, 0, stream>>>((const float4*)W, (ushort4*)wh, n4w);

    k_gate<<<NTOK / 32, 256, 0, stream>>>(x, Wg, bg, b, out, scores2, lists, counts, xh);

    // rank-0 pass then rank-1 pass (stream-ordered -> race-free RMW).
    // worst case per pass: sum_e ceil(c_e/128)*8 <= (64+7)*8 = 568 <= 576
    k_gemm<<<576, 256, 0, stream>>>(xh, wh, counts,     lists,            scores2, out);
    k_gemm<<<576, 256, 0, stream>>>(xh, wh, counts + 8, lists + 8 * NTOK, scores2, out);
}